// Round 1
// baseline (227.566 us; speedup 1.0000x reference)
//
#include <hip/hip_runtime.h>

#define ROW_LEN 2048
#define BLOCK   256
#define EPS     1e-5f

__global__ __launch_bounds__(BLOCK) void RMSNorm_56607668961691_kernel(
    const float* __restrict__ x,
    const float* __restrict__ g,
    float* __restrict__ out)
{
    const int row = blockIdx.x;
    const int tid = threadIdx.x;

    const float4* __restrict__ xr   = reinterpret_cast<const float4*>(x + (size_t)row * ROW_LEN);
    float4* __restrict__       outr = reinterpret_cast<float4*>(out + (size_t)row * ROW_LEN);
    const float4* __restrict__ gv   = reinterpret_cast<const float4*>(g);

    // 2048 floats = 512 float4 per row; 256 threads -> 2 float4 each, coalesced.
    float4 a = xr[tid];
    float4 b = xr[tid + BLOCK];

    float ss = a.x * a.x + a.y * a.y + a.z * a.z + a.w * a.w
             + b.x * b.x + b.y * b.y + b.z * b.z + b.w * b.w;

    // 64-lane wave reduction
    #pragma unroll
    for (int off = 32; off > 0; off >>= 1)
        ss += __shfl_down(ss, off, 64);

    __shared__ float wave_sums[BLOCK / 64];
    const int wave = tid >> 6;
    const int lane = tid & 63;
    if (lane == 0) wave_sums[wave] = ss;
    __syncthreads();

    const float total = wave_sums[0] + wave_sums[1] + wave_sums[2] + wave_sums[3];
    const float scale = rsqrtf(total * (1.0f / (float)ROW_LEN) + EPS);

    const float4 ga = gv[tid];
    const float4 gb = gv[tid + BLOCK];

    float4 oa, ob;
    oa.x = a.x * scale * ga.x;
    oa.y = a.y * scale * ga.y;
    oa.z = a.z * scale * ga.z;
    oa.w = a.w * scale * ga.w;
    ob.x = b.x * scale * gb.x;
    ob.y = b.y * scale * gb.y;
    ob.z = b.z * scale * gb.z;
    ob.w = b.w * scale * gb.w;

    outr[tid]         = oa;
    outr[tid + BLOCK] = ob;
}

extern "C" void kernel_launch(void* const* d_in, const int* in_sizes, int n_in,
                              void* d_out, int out_size, void* d_ws, size_t ws_size,
                              hipStream_t stream) {
    const float* x = (const float*)d_in[0];
    const float* g = (const float*)d_in[1];
    float* out = (float*)d_out;

    const int rows = in_sizes[0] / ROW_LEN;   // 4*4096 = 16384
    RMSNorm_56607668961691_kernel<<<rows, BLOCK, 0, stream>>>(x, g, out);
}